// Round 7
// baseline (15998.830 us; speedup 1.0000x reference)
//
#include <hip/hip_runtime.h>
#include <cstddef>
#include <cstdint>

#define T_STEPS 256
#define BATCH   512
#define NIN     128
#define NHID    1024

typedef _Float16 half8  __attribute__((ext_vector_type(8)));
typedef float    float4v __attribute__((ext_vector_type(4)));

__device__ __forceinline__ float sigmoid_f(float x) { return 1.0f / (1.0f + __expf(-x)); }
__device__ __forceinline__ float tanh_f(float x) {
    float ax = fabsf(x);
    float t  = __expf(-2.0f * ax);
    float r  = (1.0f - t) / (1.0f + t);
    return copysignf(r, x);
}

// ---------------------------------------------------------------------------
// Fragment layouts (16x16x32 f16 MFMA):
//   frag tile (16 rows x 32 k) = 1KB: halves index lane*8 + j,
//   value = A[r = lane&15][k = (lane>>4)*8 + j]
// Activations (plain fp16): [mtile 32][ktile 32][512 halves]   (1 MB)
// Weights (fp16 hi/lo):     [p 2][ub 64][gate 4][ktile 64][512] (32 MB)
// c arrays (fp32):          [mtile 32][ub 64][lane 64][4 floats] (2 MB)
// 2-product scheme: z = A*(Bh+Bl) -> weights fp32-exact, act err ~2^-11 fresh
// per step (non-amplifying: forget-gate contraction 0.73, Jacobians <=0.25).
// ---------------------------------------------------------------------------

__global__ __launch_bounds__(256)
void convert_weights(const float* __restrict__ k1, const float* __restrict__ k2,
                     _Float16* __restrict__ wf1, _Float16* __restrict__ wf2)
{
    __shared__ float ws2[32][17];
    const int kt    = blockIdx.x;     // 0..63
    const int ub    = blockIdx.y;     // 0..63
    const int layer = blockIdx.z;
    const float* src = layer ? k2 : k1;
    _Float16*    dst = layer ? wf2 : wf1;
    const int t = threadIdx.x;
    const size_t WPS = (size_t)64 * 4 * 64 * 512;
    for (int g = 0; g < 4; ++g) {
        for (int i = 0; i < 512; i += 256) {
            const int idx = t + i;
            const int kk = idx >> 4, n = idx & 15;
            ws2[kk][n] = src[(size_t)(kt * 32 + kk) * 4096 + g * 1024 + ub * 16 + n];
        }
        __syncthreads();
        const size_t base = (((size_t)ub * 4 + g) * 64 + kt) * 512;
        for (int i = 0; i < 512; i += 256) {
            const int idx = t + i;
            const int lane = idx >> 3, j = idx & 7;
            const float v = ws2[(lane >> 4) * 8 + j][lane & 15];
            const _Float16 hi = (_Float16)v;
            dst[base + idx]       = hi;
            dst[WPS + base + idx] = (_Float16)(v - (float)hi);
        }
        __syncthreads();
    }
}

// ---------------------------------------------------------------------------
// proj appendix (runs in L1-role WGs after the GEMM):
// relu(x_t @ W + b) -> frag fp16.  256 WGs, each a 16m x 128u tile.
// ---------------------------------------------------------------------------
__device__ __forceinline__ void proj_append(
    const float* __restrict__ x, const float* __restrict__ W,
    const float* __restrict__ bias, _Float16* __restrict__ pf,
    int tstep, int id, char* smem)
{
    float (*ws)[68]  = (float(*)[68])smem;              // [128][68]  34816 B
    float (*xs)[132] = (float(*)[132])(smem + 34816);   // [16][132]   8448 B
    float (*zl)[132] = (float(*)[132])(smem + 43264);   // [16][132]   8448 B

    const int t = threadIdx.x;
    const int mrow = id & 31;
    const int uc   = id >> 5;          // 0..7
    __syncthreads();                   // LDS reuse after lstm_body
    {
        const int m = t >> 4, kq = t & 15;
        const float* xr = x + (size_t)(mrow * 16 + m) * (T_STEPS * NIN)
                            + (size_t)tstep * NIN + kq * 8;
        *(float4v*)&xs[m][kq * 8]     = *(const float4v*)(xr);
        *(float4v*)&xs[m][kq * 8 + 4] = *(const float4v*)(xr + 4);
    }
    for (int h = 0; h < 2; ++h) {
        __syncthreads();
#pragma unroll
        for (int i = 0; i < 8; ++i) {
            const int idx = t + i * 256;
            const int k = idx >> 4, u4 = idx & 15;
            *(float4v*)&ws[k][u4 * 4] =
                *(const float4v*)(W + (size_t)k * NHID + uc * 128 + h * 64 + u4 * 4);
        }
        __syncthreads();
        const int m = t >> 4, u4 = t & 15;
        float4v acc = {0.f, 0.f, 0.f, 0.f};
#pragma unroll 4
        for (int k = 0; k < NIN; ++k) {
            const float a = xs[m][k];
            const float4v wv = *(const float4v*)&ws[k][u4 * 4];
#pragma unroll
            for (int c = 0; c < 4; ++c) acc[c] = fmaf(a, wv[c], acc[c]);
        }
        const float4v bv = *(const float4v*)&bias[uc * 128 + h * 64 + u4 * 4];
#pragma unroll
        for (int c = 0; c < 4; ++c)
            zl[m][h * 64 + u4 * 4 + c] = fmaxf(acc[c] + bv[c], 0.0f);
    }
    __syncthreads();
    // frag-out: wave w handles u-subtile w (32 u each)
    const int w = t >> 6, l = t & 63;
    const int m16 = l & 15, jb = (l >> 4) * 8;
    half8 hv;
#pragma unroll
    for (int j = 0; j < 8; ++j)
        hv[j] = (_Float16)zl[m16][w * 32 + jb + j];
    const size_t off = ((size_t)mrow * 32 + (uc * 4 + w)) * 512 + l * 8;
    *(half8*)(pf + off) = hv;
}

// ---------------------------------------------------------------------------
// LSTM task body (256 threads = 4 waves = nh x kh).  Wave: 64m x 16u x 4g,
// K-half 1024 (32 kt).  2-product: acts fp16, weights hi+lo.
// Register-double-buffered direct-from-global frags.
// ---------------------------------------------------------------------------
__device__ __forceinline__ void lstm_body(
    const _Float16* __restrict__ A0, const _Float16* __restrict__ A1,
    const _Float16* __restrict__ Wf, const float* __restrict__ bias,
    const float* __restrict__ c_old, float* __restrict__ c_new,
    _Float16* __restrict__ hout, float* __restrict__ out_f32,
    int id, char* smem)
{
    float (*red)[4096] = (float(*)[4096])smem;           // [2][4096]
    float (*hl)[36]    = (float(*)[36])(smem + 32768);   // [64][36]

    const int tid = threadIdx.x;
    const int w = tid >> 6, l = tid & 63;
    const int nh = w & 1, kh = w >> 1;
    const int xcd = id & 7;
    const int s   = id >> 3;
    const int mgrp = s & 7;
    const int wgu  = xcd * 4 + (s >> 3);
    const int ub   = wgu * 2 + nh;
    const int q = l >> 4, n = l & 15;

    const _Float16* Af = kh ? A1 : A0;
    const size_t WPS = (size_t)64 * 4 * 64 * 512;

    const char* aB[4];
    const char* bB[2][4];
#pragma unroll
    for (int mt = 0; mt < 4; ++mt)
        aB[mt] = (const char*)(Af + (size_t)(mgrp * 4 + mt) * 32 * 512);
#pragma unroll
    for (int p = 0; p < 2; ++p)
#pragma unroll
        for (int g = 0; g < 4; ++g)
            bB[p][g] = (const char*)(Wf + p * WPS + (((size_t)ub * 4 + g) * 64 + kh * 32) * 512);
    const uint32_t lo16 = (uint32_t)l * 16;

    half8 Ab[2][4], Bb[2][2][4];
    float4v acc[4][4];
#pragma unroll
    for (int mt = 0; mt < 4; ++mt)
#pragma unroll
        for (int g = 0; g < 4; ++g)
            acc[mt][g] = (float4v){0.f, 0.f, 0.f, 0.f};

    auto loadbuf = [&](int kt, int buf) {
        const uint32_t off = lo16 + (uint32_t)((kt < 31) ? kt : 31) * 1024u;
#pragma unroll
        for (int mt = 0; mt < 4; ++mt)
            Ab[buf][mt] = *(const half8*)(aB[mt] + off);
#pragma unroll
        for (int p = 0; p < 2; ++p)
#pragma unroll
            for (int g = 0; g < 4; ++g)
                Bb[buf][p][g] = *(const half8*)(bB[p][g] + off);
    };
    auto mstep = [&](int buf) {
#pragma unroll
        for (int g = 0; g < 4; ++g)
#pragma unroll
            for (int mt = 0; mt < 4; ++mt)
                acc[mt][g] = __builtin_amdgcn_mfma_f32_16x16x32_f16(Ab[buf][mt], Bb[buf][0][g], acc[mt][g], 0, 0, 0);
#pragma unroll
        for (int g = 0; g < 4; ++g)
#pragma unroll
            for (int mt = 0; mt < 4; ++mt)
                acc[mt][g] = __builtin_amdgcn_mfma_f32_16x16x32_f16(Ab[buf][mt], Bb[buf][1][g], acc[mt][g], 0, 0, 0);
    };

    loadbuf(0, 0);
    for (int kt = 0; kt < 32; kt += 2) {
        loadbuf(kt + 1, 1);
        mstep(0);
        loadbuf(kt + 2, 0);
        mstep(1);
    }

    // k-half reduction
    __syncthreads();
    if (kh == 1) {
#pragma unroll
        for (int mt = 0; mt < 4; ++mt)
#pragma unroll
            for (int g = 0; g < 4; ++g)
#pragma unroll
                for (int r = 0; r < 4; ++r)
                    red[nh][((mt * 4 + g) * 4 + r) * 64 + l] = acc[mt][g][r];
    }
    __syncthreads();
    if (kh == 0) {
#pragma unroll
        for (int mt = 0; mt < 4; ++mt)
#pragma unroll
            for (int g = 0; g < 4; ++g)
#pragma unroll
                for (int r = 0; r < 4; ++r)
                    acc[mt][g][r] += red[nh][((mt * 4 + g) * 4 + r) * 64 + l];

        const int unit = ub * 16 + n;
        const float bi = bias[unit];
        const float bj = bias[NHID + unit];
        const float bf = bias[2 * NHID + unit];
        const float bo = bias[3 * NHID + unit];
#pragma unroll
        for (int mt = 0; mt < 4; ++mt) {
            const int mtglob = mgrp * 4 + mt;
            const size_t cbase = ((size_t)mtglob * 64 + ub) * 256 + l * 4;
            const float4v cv = *(const float4v*)(c_old + cbase);
            float4v cn;
            float hn[4];
#pragma unroll
            for (int r = 0; r < 4; ++r) {
                const float zi = acc[mt][0][r] + bi;
                const float zj = acc[mt][1][r] + bj;
                const float zf = acc[mt][2][r] + bf;
                const float zo = acc[mt][3][r] + bo;
                const float c = cv[r] * sigmoid_f(zf + 1.0f) + sigmoid_f(zi) * tanh_f(zj);
                cn[r] = c;
                hn[r] = tanh_f(c) * sigmoid_f(zo);
            }
            *(float4v*)(c_new + cbase) = cn;
#pragma unroll
            for (int r = 0; r < 4; ++r)
                hl[mt * 16 + q * 4 + r][nh * 16 + n] = hn[r];
            if (out_f32) {
#pragma unroll
                for (int r = 0; r < 4; ++r)
                    out_f32[(size_t)(mgrp * 64 + mt * 16 + q * 4 + r) * NHID + unit] = hn[r];
            }
        }
    }
    __syncthreads();
    // frag-out of new h: wave w handles m-tile w
    const int mloc = w * 16 + n;
    const int q8 = q * 8;
    const float4v v0 = *(const float4v*)&hl[mloc][q8];
    const float4v v1 = *(const float4v*)&hl[mloc][q8 + 4];
    half8 hv;
#pragma unroll
    for (int jx = 0; jx < 4; ++jx) {
        hv[jx]     = (_Float16)v0[jx];
        hv[jx + 4] = (_Float16)v1[jx];
    }
    const size_t off = (((size_t)(mgrp * 4 + w)) * 32 + wgu) * 512 + l * 8;
    *(half8*)(hout + off) = hv;
}

// ---------------------------------------------------------------------------
// One phase, grid 512 (exactly 2 WGs/CU):
//   bid 0..255   : L1(t1) GEMM, then proj(tp) appendix
//   bid 256..511 : L2(t2) GEMM
// ---------------------------------------------------------------------------
__global__ __launch_bounds__(256, 2)
void phase_kernel(const float* __restrict__ x, const float* __restrict__ W_h,
                  const float* __restrict__ b_h,
                  const _Float16* __restrict__ pf_in, _Float16* __restrict__ pf_out,
                  const _Float16* __restrict__ wf1, const float* __restrict__ b1,
                  const float* __restrict__ c1_in, float* __restrict__ c1_out,
                  const _Float16* __restrict__ h1_in, _Float16* __restrict__ h1_out,
                  const _Float16* __restrict__ wf2, const float* __restrict__ b2,
                  const float* __restrict__ c2_in, float* __restrict__ c2_out,
                  const _Float16* __restrict__ h2_in, _Float16* __restrict__ h2_out,
                  float* __restrict__ out_f32, int t1, int t2, int tp)
{
    __shared__ __align__(16) char smem[62464];
    const int bid = blockIdx.x;
    if (bid < 256) {
        if (t1 >= 0 && t1 <= 255)
            lstm_body(pf_in, h1_in, wf1, b1, c1_in, c1_out,
                      h1_out, nullptr, bid, smem);
        if (tp >= 0 && tp <= 255)
            proj_append(x, W_h, b_h, pf_out, tp, bid, smem);
    } else {
        if (t2 >= 0 && t2 <= 255)
            lstm_body(h1_in, h2_in, wf2, b2, c2_in, c2_out,
                      h2_out, out_f32, bid - 256, smem);
    }
}

// ---------------------------------------------------------------------------
extern "C" void kernel_launch(void* const* d_in, const int* in_sizes, int n_in,
                              void* d_out, int out_size, void* d_ws, size_t ws_size,
                              hipStream_t stream)
{
    const float* x   = (const float*)d_in[0];
    const float* W_h = (const float*)d_in[1];
    const float* b_h = (const float*)d_in[2];
    const float* k1  = (const float*)d_in[3];
    const float* b1  = (const float*)d_in[4];
    const float* k2  = (const float*)d_in[5];
    const float* b2  = (const float*)d_in[6];
    float* out = (float*)d_out;

    const size_t MB = 1024 * 1024;
    uint8_t* wsb = (uint8_t*)d_ws;
    // Zero block (first 6 MB) = exactly the buffers read before first write:
    //   c1f[0] (2MB), h1f[0] (1MB)  -- first L1 at phase 0, pi=0
    //   c2f[1] (2MB), h2f[1] (1MB)  -- first L2 at phase 1, pi=1
    float*    c1f[2] = {(float*)(wsb + 0 * MB),    (float*)(wsb + 6 * MB)};
    _Float16* h1f[2] = {(_Float16*)(wsb + 2 * MB), (_Float16*)(wsb + 8 * MB)};
    float*    c2f[2] = {(float*)(wsb + 9 * MB),    (float*)(wsb + 3 * MB)};
    _Float16* h2f[2] = {(_Float16*)(wsb + 11 * MB),(_Float16*)(wsb + 5 * MB)};
    _Float16* pf[2]  = {(_Float16*)(wsb + 12 * MB), (_Float16*)(wsb + 13 * MB)};
    _Float16* wf1 = (_Float16*)(wsb + 14 * MB);
    _Float16* wf2 = (_Float16*)(wsb + 46 * MB);   // ends at 78 MB

    hipMemsetAsync(d_ws, 0, 6 * MB, stream);
    convert_weights<<<dim3(64, 64, 2), 256, 0, stream>>>(k1, k2, wf1, wf2);

    // pre-dispatch: proj(0) only (GEMMs disabled via t1=t2=-1)
    phase_kernel<<<512, 256, 0, stream>>>(x, W_h, b_h,
        pf[0], pf[0], wf1, b1, c1f[0], c1f[1], h1f[0], h1f[1],
        wf2, b2, c2f[0], c2f[1], h2f[0], h2f[1], nullptr, -1, -1, 0);

    for (int p = 0; p <= 256; ++p) {
        const int pi = p & 1, po = pi ^ 1;
        phase_kernel<<<512, 256, 0, stream>>>(x, W_h, b_h,
            pf[pi], pf[po],
            wf1, b1, c1f[pi], c1f[po], h1f[pi], h1f[po],
            wf2, b2, c2f[pi], c2f[po], h2f[pi], h2f[po],
            (p == 256) ? out : nullptr, p, p - 1, p + 1);
    }
}